// Round 11
// baseline (212.844 us; speedup 1.0000x reference)
//
#include <hip/hip_runtime.h>
#include <math.h>

#define N_OUT 32
#define D_OUT 32
#define N_IN 2048
#define D_IN 16
#define BATCH 64
#define J 1024           // N_OUT*D_OUT

typedef __attribute__((ext_vector_type(8))) short short8;   // 8 bf16 (4 VGPR)
typedef __attribute__((ext_vector_type(4))) float f32x4;    // MFMA C/D

// f32 -> bf16 RNE
__device__ __forceinline__ unsigned short f2bf(float f) {
  unsigned int x = __float_as_uint(f);
  return (unsigned short)((x + 0x7FFFu + ((x >> 16) & 1u)) >> 16);
}

// 16B-unit swizzle inside one n-tile (2048 units): XOR bit0 with bit3
__device__ __forceinline__ int wp(int u) { return u ^ ((u >> 3) & 1); }

__device__ __forceinline__ void pack_col(const float* wc, uint4& d0, uint4& d1) {
  d0.x = (unsigned)f2bf(wc[0])  | ((unsigned)f2bf(wc[1])  << 16);
  d0.y = (unsigned)f2bf(wc[2])  | ((unsigned)f2bf(wc[3])  << 16);
  d0.z = (unsigned)f2bf(wc[4])  | ((unsigned)f2bf(wc[5])  << 16);
  d0.w = (unsigned)f2bf(wc[6])  | ((unsigned)f2bf(wc[7])  << 16);
  d1.x = (unsigned)f2bf(wc[8])  | ((unsigned)f2bf(wc[9])  << 16);
  d1.y = (unsigned)f2bf(wc[10]) | ((unsigned)f2bf(wc[11]) << 16);
  d1.z = (unsigned)f2bf(wc[12]) | ((unsigned)f2bf(wc[13]) << 16);
  d1.w = (unsigned)f2bf(wc[14]) | ((unsigned)f2bf(wc[15]) << 16);
}

// MODE 0: load W f32, convert in-kernel, AND write bf16 copies out (pass 0)
// MODE 1: reg-staged pre-converted Wbf/ubf (passes 1,2)
// MODE 2: like MODE 0 without writeout (fallback when ws too small)
//
// Block: 1024 threads (16 waves) = 16 b x 1024 j x NCHUNK n.
// NCHUNK=16 -> grid 512 -> 2 blocks/CU (VGPR~44 <= 64, LDS ~70KB*2 <= 160KB):
// two co-resident barrier domains overlap each other's stalls.
// MFMA swapped: D[j_loc][b_loc] = sum_i W[n][i][j] * u[b][n][i], K=16 of 32.
template<bool HAS_V, int MODE, int NCHUNK>
__global__ __launch_bounds__(1024, 1)
void pass_kernel(const float* __restrict__ uf, const float* __restrict__ Wf,
                 short* __restrict__ Wbf, short* __restrict__ ubf,
                 const float* __restrict__ vin, float* __restrict__ part)
{
  __shared__ uint4 Wt[2][2048];     // double-buffered W tile (2 x 32KB)
  __shared__ float al[2][32][18];   // logits -> c, [parity][o][b_local]

  const int t  = threadIdx.x;
  const int l  = t & 63;
  const int w  = t >> 6;            // wave 0..15
  const int bid = blockIdx.x;
  const int bq = (bid >> 3) & 3;                    // b quadrant (16 b)
  const int cx = (bid & 7) | ((bid >> 5) << 3);     // chunk (XCD-grouped)
  const int n0 = cx * NCHUNK;

  const int bl = l & 15;            // D col = b_local
  const int b  = bq * 16 + bl;      // global b
  const int h  = l >> 4;            // 0..3: D rows 4h..4h+3
  const int hA = h & 1;             // k-half (i 0-7 / 8-15) for lanes < 32
  const bool ld = (l < 32);

  // v fragments (n-invariant): v[b][jt*16 + 4h + r]
  f32x4 vf[4];
  if (HAS_V) {
    #pragma unroll
    for (int q = 0; q < 4; ++q)
      vf[q] = *reinterpret_cast<const f32x4*>(vin + (size_t)b * J + (w*4+q)*16 + h*4);
  }

  int aoff[4];
  #pragma unroll
  for (int q = 0; q < 4; ++q) aoff[q] = wp(2 * ((w*4+q) * 16 + bl) + hA);

  f32x4 acc[4];
  #pragma unroll
  for (int q = 0; q < 4; ++q) acc[q] = f32x4{0.f, 0.f, 0.f, 0.f};

  if constexpr (MODE == 1) {
    // ============ MODE 1: reg-staged bf16 tiles ============
    short8 Bcur = short8{0,0,0,0,0,0,0,0};
    {
      const uint4* src = reinterpret_cast<const uint4*>(Wbf + (size_t)n0 * (D_IN * J));
      Wt[0][t] = src[t];
      Wt[0][t + 1024] = src[t + 1024];
      if (ld)
        Bcur = *reinterpret_cast<const short8*>(ubf + ((size_t)b * N_IN + n0) * D_IN + hA * 8);
    }
    __syncthreads();

    for (int nn = 0; nn < NCHUNK; ++nn) {
      const int n = n0 + nn;
      const int cur = nn & 1, nxt = cur ^ 1, par = nn & 1;
      const bool more = (nn + 1 < NCHUNK);

      // 1. issue next-tile loads early (write-late below)
      uint4 s0, s1;
      short8 Bn = short8{0,0,0,0,0,0,0,0};
      if (more) {
        const uint4* src = reinterpret_cast<const uint4*>(Wbf + (size_t)(n + 1) * (D_IN * J));
        s0 = src[t];
        s1 = src[t + 1024];
        if (ld)
          Bn = *reinterpret_cast<const short8*>(ubf + ((size_t)b * N_IN + n + 1) * D_IN + hA * 8);
      }

      // 2. uhat tiles via MFMA
      f32x4 C[4];
      const uint4* buf = Wt[cur];
      #pragma unroll
      for (int q = 0; q < 4; ++q) {
        short8 A = short8{0,0,0,0,0,0,0,0};
        if (ld) A = *reinterpret_cast<const short8*>(&buf[aoff[q]]);
        f32x4 z = f32x4{0.f, 0.f, 0.f, 0.f};
        C[q] = __builtin_amdgcn_mfma_f32_16x16x32_bf16(A, Bcur, z, 0, 0, 0);
      }

      // 3. agreement a[b][o] = sum_k uhat*v
      {
        float ap[2] = {0.f, 0.f};
        #pragma unroll
        for (int q = 0; q < 4; ++q) {
          float s = C[q][0]*vf[q][0] + C[q][1]*vf[q][1] + C[q][2]*vf[q][2] + C[q][3]*vf[q][3];
          ap[q >> 1] += s;
        }
        #pragma unroll
        for (int p = 0; p < 2; ++p) {
          float s = ap[p];
          s += __shfl_xor(s, 16);
          s += __shfl_xor(s, 32);
          if (l < 16) al[par][w * 2 + p][l] = s;
        }
      }

      // 4. write-late staging into other buffer
      if (more) {
        Wt[nxt][t] = s0;
        Wt[nxt][t + 1024] = s1;
      }

      __syncthreads();   // (B) logits staged
      if (t < 512) {     // softmax over o per b: 32-lane o-groups
        int sb = t >> 5, so = t & 31;
        float x = al[par][so][sb];
        float m = x;
        #pragma unroll
        for (int k = 1; k < 32; k <<= 1) m = fmaxf(m, __shfl_xor(m, k));
        float e = __expf(x - m);
        float sm = e;
        #pragma unroll
        for (int k = 1; k < 32; k <<= 1) sm += __shfl_xor(sm, k);
        al[par][so][sb] = e / sm;
      }
      __syncthreads();   // (C) c ready
      #pragma unroll
      for (int q = 0; q < 4; ++q) {
        float c = al[par][(w * 4 + q) >> 1][bl];
        acc[q] += C[q] * c;
      }
      // no end barrier: al parity-buffered; Wt read->overwrite separated by (B)
      Bcur = Bn;
    }
  } else {
    // ============ MODE 0/2: f32 load + convert, MLP-forced ============
    const bool wq = (MODE == 0) && ((t >> 8) == bq);   // this block's Wbf quarter
    const bool uq = (MODE == 0) && (w == 0) && ld;     // wave 0 writes ubf

    short8 Bcur = short8{0,0,0,0,0,0,0,0};
    {
      float wc[16];
      const float* wsrc = Wf + (size_t)n0 * (D_IN * J) + t;
      #pragma unroll
      for (int i = 0; i < 16; ++i) wc[i] = wsrc[i * J];
      float4 a4 = {0,0,0,0}, b4 = {0,0,0,0};
      if (ld) {
        const float* up = uf + ((size_t)b * N_IN + n0) * D_IN + hA * 8;
        a4 = *reinterpret_cast<const float4*>(up);
        b4 = *reinterpret_cast<const float4*>(up + 4);
      }
      __builtin_amdgcn_sched_barrier(0);   // all loads issued before packing
      uint4 d0, d1;
      pack_col(wc, d0, d1);
      Wt[0][wp(2 * t)] = d0;
      Wt[0][wp(2 * t + 1)] = d1;
      if (wq) {
        uint4* gdst = reinterpret_cast<uint4*>(Wbf + (size_t)n0 * (D_IN * J));
        gdst[wp(2 * t)] = d0;
        gdst[wp(2 * t + 1)] = d1;
      }
      if (ld) {
        Bcur[0] = (short)f2bf(a4.x); Bcur[1] = (short)f2bf(a4.y);
        Bcur[2] = (short)f2bf(a4.z); Bcur[3] = (short)f2bf(a4.w);
        Bcur[4] = (short)f2bf(b4.x); Bcur[5] = (short)f2bf(b4.y);
        Bcur[6] = (short)f2bf(b4.z); Bcur[7] = (short)f2bf(b4.w);
        if (uq)
          *reinterpret_cast<short8*>(ubf + ((size_t)b * N_IN + n0) * D_IN + hA * 8) = Bcur;
      }
    }
    __syncthreads();

    for (int nn = 0; nn < NCHUNK; ++nn) {
      const int n = n0 + nn;
      const int cur = nn & 1, nxt = cur ^ 1, par = nn & 1;
      const bool more = (nn + 1 < NCHUNK);

      // 1. issue ALL next-tile loads, then fence the scheduler
      float wc[16];
      float4 a4 = {0,0,0,0}, b4 = {0,0,0,0};
      if (more) {
        const float* wsrc = Wf + (size_t)(n + 1) * (D_IN * J) + t;
        #pragma unroll
        for (int i = 0; i < 16; ++i) wc[i] = wsrc[i * J];
        if (ld) {
          const float* up = uf + ((size_t)b * N_IN + n + 1) * D_IN + hA * 8;
          a4 = *reinterpret_cast<const float4*>(up);
          b4 = *reinterpret_cast<const float4*>(up + 4);
        }
        __builtin_amdgcn_sched_barrier(0);
      }

      // 2. uhat tiles via MFMA
      f32x4 C[4];
      const uint4* buf = Wt[cur];
      #pragma unroll
      for (int q = 0; q < 4; ++q) {
        short8 A = short8{0,0,0,0,0,0,0,0};
        if (ld) A = *reinterpret_cast<const short8*>(&buf[aoff[q]]);
        f32x4 z = f32x4{0.f, 0.f, 0.f, 0.f};
        C[q] = __builtin_amdgcn_mfma_f32_16x16x32_bf16(A, Bcur, z, 0, 0, 0);
      }

      short8 Bn = short8{0,0,0,0,0,0,0,0};
      if (more && ld) {
        Bn[0] = (short)f2bf(a4.x); Bn[1] = (short)f2bf(a4.y);
        Bn[2] = (short)f2bf(a4.z); Bn[3] = (short)f2bf(a4.w);
        Bn[4] = (short)f2bf(b4.x); Bn[5] = (short)f2bf(b4.y);
        Bn[6] = (short)f2bf(b4.z); Bn[7] = (short)f2bf(b4.w);
      }

      if (HAS_V) {
        float ap[2] = {0.f, 0.f};
        #pragma unroll
        for (int q = 0; q < 4; ++q) {
          float s = C[q][0]*vf[q][0] + C[q][1]*vf[q][1] + C[q][2]*vf[q][2] + C[q][3]*vf[q][3];
          ap[q >> 1] += s;
        }
        #pragma unroll
        for (int p = 0; p < 2; ++p) {
          float s = ap[p];
          s += __shfl_xor(s, 16);
          s += __shfl_xor(s, 32);
          if (l < 16) al[par][w * 2 + p][l] = s;
        }
        if (more) {
          uint4 d0, d1;
          pack_col(wc, d0, d1);
          Wt[nxt][wp(2 * t)] = d0;
          Wt[nxt][wp(2 * t + 1)] = d1;
          if (wq) {
            uint4* gdst = reinterpret_cast<uint4*>(Wbf + (size_t)(n + 1) * (D_IN * J));
            gdst[wp(2 * t)] = d0;
            gdst[wp(2 * t + 1)] = d1;
          }
          if (ld && uq)
            *reinterpret_cast<short8*>(ubf + ((size_t)b * N_IN + n + 1) * D_IN + hA * 8) = Bn;
        }
        __syncthreads();   // (B)
        if (t < 512) {
          int sb = t >> 5, so = t & 31;
          float x = al[par][so][sb];
          float m = x;
          #pragma unroll
          for (int k = 1; k < 32; k <<= 1) m = fmaxf(m, __shfl_xor(m, k));
          float e = __expf(x - m);
          float sm = e;
          #pragma unroll
          for (int k = 1; k < 32; k <<= 1) sm += __shfl_xor(sm, k);
          al[par][so][sb] = e / sm;
        }
        __syncthreads();   // (C)
        #pragma unroll
        for (int q = 0; q < 4; ++q) {
          float c = al[par][(w * 4 + q) >> 1][bl];
          acc[q] += C[q] * c;
        }
      } else {
        #pragma unroll
        for (int q = 0; q < 4; ++q) acc[q] += C[q];
        if (more) {
          uint4 d0, d1;
          pack_col(wc, d0, d1);
          Wt[nxt][wp(2 * t)] = d0;
          Wt[nxt][wp(2 * t + 1)] = d1;
          if (wq) {
            uint4* gdst = reinterpret_cast<uint4*>(Wbf + (size_t)(n + 1) * (D_IN * J));
            gdst[wp(2 * t)] = d0;
            gdst[wp(2 * t + 1)] = d1;
          }
          if (ld && uq)
            *reinterpret_cast<short8*>(ubf + ((size_t)b * N_IN + n + 1) * D_IN + hA * 8) = Bn;
        }
        __syncthreads();
      }
      Bcur = Bn;
    }
  }

  // epilogue: part[cx][j][b] (transposed -> coalesced b-fast writes)
  #pragma unroll
  for (int q = 0; q < 4; ++q) {
    int jbase = (w * 4 + q) * 16 + h * 4;
    #pragma unroll
    for (int r = 0; r < 4; ++r)
      part[((size_t)cx * J + jbase + r) * 64 + b] = acc[q][r];
  }
}

// Fused chunk-reduce + squash. grid = 128 (o x b-quadrant), 1024 threads.
template<int NC>
__global__ __launch_bounds__(1024)
void rsq_kernel(const float* __restrict__ part, const float* __restrict__ addv,
                float* __restrict__ out, float prescale)
{
  __shared__ float ps[2][32][17];
  __shared__ float vl[32][17];
  __shared__ float scl[16];
  const int o  = blockIdx.x >> 2;
  const int bq = blockIdx.x & 3;
  const int t  = threadIdx.x;
  {
    const int bb = t & 15;
    const int kk = (t >> 4) & 31;
    const int ch = t >> 9;         // 0/1
    const float* p = part + (size_t)(o * 32 + kk) * 64 + bq * 16 + bb;
    float s = 0.f;
    #pragma unroll 8
    for (int c = ch * (NC / 2); c < (ch + 1) * (NC / 2); ++c)
      s += p[(size_t)c * (J * 64)];
    ps[ch][kk][bb] = s;
  }
  __syncthreads();
  if (t < 512) {
    int kk = t >> 4, bb = t & 15;
    vl[kk][bb] = (ps[0][kk][bb] + ps[1][kk][bb]) * prescale;
  }
  __syncthreads();
  if (t < 16) {
    float n2 = 0.f;
    #pragma unroll
    for (int k = 0; k < 32; ++k) { float x = vl[k][t]; n2 += x * x; }
    scl[t] = sqrtf(n2) / (1.f + n2);
  }
  __syncthreads();
  if (t < 512) {
    int bb = t >> 5, kk = t & 31;
    int idx = (bq * 16 + bb) * J + o * 32 + kk;
    float val = scl[bb] * vl[kk][bb];
    if (addv) val += addv[idx];
    out[idx] = val;
  }
}

extern "C" void kernel_launch(void* const* d_in, const int* in_sizes, int n_in,
                              void* d_out, int out_size, void* d_ws, size_t ws_size,
                              hipStream_t stream)
{
  const float* u = (const float*)d_in[0];
  const float* W = (const float*)d_in[1];
  float* out = (float*)d_out;
  char* ws = (char*)d_ws;

  const size_t WBF_B = (size_t)N_IN * D_IN * J * 2;        // 64 MB
  const size_t UBF_B = (size_t)BATCH * N_IN * D_IN * 2;    // 4 MB
  const size_t SMALL = 2ull * BATCH * J * 4;               // v0+vs
  const size_t PART128 = (size_t)128 * J * 64 * 4;         // 33.5 MB (NC=128)
  const size_t PART64  = (size_t)64 * J * 64 * 4;          // 16.7 MB (NC=64)

  if (ws_size >= WBF_B + UBF_B + PART128 + SMALL) {
    // preferred: NCHUNK=16 -> grid 512 -> 2 blocks/CU
    short* Wbf = (short*)ws;
    short* ubf = (short*)(ws + WBF_B);
    float* part = (float*)(ws + WBF_B + UBF_B);
    float* v0 = part + (size_t)128 * J * 64;
    float* vs = v0 + BATCH * J;
    pass_kernel<false, 0, 16><<<512, 1024, 0, stream>>>(u, W, Wbf, ubf, nullptr, part);
    rsq_kernel<128><<<128, 1024, 0, stream>>>(part, nullptr, v0, 1.f / 32.f);
    pass_kernel<true, 1, 16><<<512, 1024, 0, stream>>>(u, W, Wbf, ubf, v0, part);
    rsq_kernel<128><<<128, 1024, 0, stream>>>(part, v0, vs, 1.f);
    pass_kernel<true, 1, 16><<<512, 1024, 0, stream>>>(u, W, Wbf, ubf, vs, part);
    rsq_kernel<128><<<128, 1024, 0, stream>>>(part, nullptr, out, 1.f);
  } else if (ws_size >= WBF_B + UBF_B + PART64 + SMALL) {
    short* Wbf = (short*)ws;
    short* ubf = (short*)(ws + WBF_B);
    float* part = (float*)(ws + WBF_B + UBF_B);
    float* v0 = part + (size_t)64 * J * 64;
    float* vs = v0 + BATCH * J;
    pass_kernel<false, 0, 32><<<256, 1024, 0, stream>>>(u, W, Wbf, ubf, nullptr, part);
    rsq_kernel<64><<<128, 1024, 0, stream>>>(part, nullptr, v0, 1.f / 32.f);
    pass_kernel<true, 1, 32><<<256, 1024, 0, stream>>>(u, W, Wbf, ubf, v0, part);
    rsq_kernel<64><<<128, 1024, 0, stream>>>(part, v0, vs, 1.f);
    pass_kernel<true, 1, 32><<<256, 1024, 0, stream>>>(u, W, Wbf, ubf, vs, part);
    rsq_kernel<64><<<128, 1024, 0, stream>>>(part, nullptr, out, 1.f);
  } else if (ws_size >= PART64 + SMALL) {
    float* part = (float*)ws;
    float* v0 = part + (size_t)64 * J * 64;
    float* vs = v0 + BATCH * J;
    pass_kernel<false, 2, 32><<<256, 1024, 0, stream>>>(u, W, nullptr, nullptr, nullptr, part);
    rsq_kernel<64><<<128, 1024, 0, stream>>>(part, nullptr, v0, 1.f / 32.f);
    pass_kernel<true, 2, 32><<<256, 1024, 0, stream>>>(u, W, nullptr, nullptr, v0, part);
    rsq_kernel<64><<<128, 1024, 0, stream>>>(part, v0, vs, 1.f);
    pass_kernel<true, 2, 32><<<256, 1024, 0, stream>>>(u, W, nullptr, nullptr, vs, part);
    rsq_kernel<64><<<128, 1024, 0, stream>>>(part, nullptr, out, 1.f);
  } else {
    float* part = (float*)ws;
    float* v0 = part + (size_t)16 * J * 64;
    float* vs = v0 + BATCH * J;
    pass_kernel<false, 2, 128><<<64, 1024, 0, stream>>>(u, W, nullptr, nullptr, nullptr, part);
    rsq_kernel<16><<<128, 1024, 0, stream>>>(part, nullptr, v0, 1.f / 32.f);
    pass_kernel<true, 2, 128><<<64, 1024, 0, stream>>>(u, W, nullptr, nullptr, v0, part);
    rsq_kernel<16><<<128, 1024, 0, stream>>>(part, v0, vs, 1.f);
    pass_kernel<true, 2, 128><<<64, 1024, 0, stream>>>(u, W, nullptr, nullptr, vs, part);
    rsq_kernel<16><<<128, 1024, 0, stream>>>(part, nullptr, out, 1.f);
  }
}

// Round 12
// 182.583 us; speedup vs baseline: 1.1657x; 1.1657x over previous
//
#include <hip/hip_runtime.h>
#include <math.h>

#define N_OUT 32
#define D_OUT 32
#define N_IN 2048
#define D_IN 16
#define BATCH 64
#define J 1024           // N_OUT*D_OUT

typedef __attribute__((ext_vector_type(8))) short short8;   // 8 bf16 (4 VGPR)
typedef __attribute__((ext_vector_type(4))) float f32x4;    // MFMA C/D

// f32 -> bf16 RNE
__device__ __forceinline__ unsigned short f2bf(float f) {
  unsigned int x = __float_as_uint(f);
  return (unsigned short)((x + 0x7FFFu + ((x >> 16) & 1u)) >> 16);
}

// 16B-unit swizzle inside one n-tile (2048 units): XOR bit0 with bit3
__device__ __forceinline__ int wp(int u) { return u ^ ((u >> 3) & 1); }

__device__ __forceinline__ void pack_col(const float* wc, uint4& d0, uint4& d1) {
  d0.x = (unsigned)f2bf(wc[0])  | ((unsigned)f2bf(wc[1])  << 16);
  d0.y = (unsigned)f2bf(wc[2])  | ((unsigned)f2bf(wc[3])  << 16);
  d0.z = (unsigned)f2bf(wc[4])  | ((unsigned)f2bf(wc[5])  << 16);
  d0.w = (unsigned)f2bf(wc[6])  | ((unsigned)f2bf(wc[7])  << 16);
  d1.x = (unsigned)f2bf(wc[8])  | ((unsigned)f2bf(wc[9])  << 16);
  d1.y = (unsigned)f2bf(wc[10]) | ((unsigned)f2bf(wc[11]) << 16);
  d1.z = (unsigned)f2bf(wc[12]) | ((unsigned)f2bf(wc[13]) << 16);
  d1.w = (unsigned)f2bf(wc[14]) | ((unsigned)f2bf(wc[15]) << 16);
}

// MODE 0: load W f32, convert in-kernel, AND write bf16 copies out (pass 0)
// MODE 1: reg-staged pre-converted Wbf/ubf, 2 n per barrier pair (passes 1,2)
// MODE 2: like MODE 0 without writeout (fallback when ws too small)
//
// Block: 1024 threads (16 waves) = 16 b x 1024 j x NCHUNK n. 1 block/CU
// (VGPR+AGPR > 64 rules out 2 blocks/CU -- measured r6/r7/r11), so the lever
// is fewer barriers per n: MODE1 quad-buffers W (128KB LDS) and does two n
// per (B)+(C) barrier pair, softmax using all 1024 threads.
// MFMA swapped: D[j_loc][b_loc] = sum_i W[n][i][j] * u[b][n][i], K=16 of 32.
template<bool HAS_V, int MODE, int NCHUNK>
__global__ __launch_bounds__(1024, 1)
void pass_kernel(const float* __restrict__ uf, const float* __restrict__ Wf,
                 short* __restrict__ Wbf, short* __restrict__ ubf,
                 const float* __restrict__ vin, float* __restrict__ part)
{
  constexpr int NBUF = (MODE == 1) ? 4 : 2;
  __shared__ uint4 Wt[NBUF][2048];        // W tiles (32KB each)
  __shared__ float al[2][2][32][18];      // logits -> c, [parity][npair][o][b]

  const int t  = threadIdx.x;
  const int l  = t & 63;
  const int w  = t >> 6;            // wave 0..15
  const int bid = blockIdx.x;
  const int bq = (bid >> 3) & 3;                    // b quadrant (16 b)
  const int cx = (bid & 7) | ((bid >> 5) << 3);     // chunk (XCD-grouped)
  const int n0 = cx * NCHUNK;

  const int bl = l & 15;            // D col = b_local
  const int b  = bq * 16 + bl;      // global b
  const int h  = l >> 4;            // 0..3: D rows 4h..4h+3
  const int hA = h & 1;             // k-half (i 0-7 / 8-15) for lanes < 32
  const bool ld = (l < 32);

  // v fragments (n-invariant): v[b][jt*16 + 4h + r]
  f32x4 vf[4];
  if (HAS_V) {
    #pragma unroll
    for (int q = 0; q < 4; ++q)
      vf[q] = *reinterpret_cast<const f32x4*>(vin + (size_t)b * J + (w*4+q)*16 + h*4);
  }

  int aoff[4];
  #pragma unroll
  for (int q = 0; q < 4; ++q) aoff[q] = wp(2 * ((w*4+q) * 16 + bl) + hA);

  f32x4 acc[4];
  #pragma unroll
  for (int q = 0; q < 4; ++q) acc[q] = f32x4{0.f, 0.f, 0.f, 0.f};

  if constexpr (MODE == 1) {
    // ============ MODE 1: paired-n, quad-buffered ============
    constexpr int NS = NCHUNK / 2;
    short8 Ba = short8{0,0,0,0,0,0,0,0}, Bb = short8{0,0,0,0,0,0,0,0};
    {
      const uint4* srcA = reinterpret_cast<const uint4*>(Wbf + (size_t)n0 * (D_IN * J));
      Wt[0][t] = srcA[t];
      Wt[0][t + 1024] = srcA[t + 1024];
      const uint4* srcB = reinterpret_cast<const uint4*>(Wbf + (size_t)(n0 + 1) * (D_IN * J));
      Wt[1][t] = srcB[t];
      Wt[1][t + 1024] = srcB[t + 1024];
      if (ld) {
        Ba = *reinterpret_cast<const short8*>(ubf + ((size_t)b * N_IN + n0) * D_IN + hA * 8);
        Bb = *reinterpret_cast<const short8*>(ubf + ((size_t)b * N_IN + n0 + 1) * D_IN + hA * 8);
      }
    }
    __syncthreads();

    for (int ss = 0; ss < NS; ++ss) {
      const int na = n0 + 2 * ss;
      const int p = ss & 1;          // current quad pair base 2p
      const int par = ss & 1;
      const bool more = (ss + 1 < NS);

      // 1. issue next-pair loads early (write-late below)
      uint4 sa0, sa1, sb0, sb1;
      short8 Bna = short8{0,0,0,0,0,0,0,0}, Bnb = short8{0,0,0,0,0,0,0,0};
      if (more) {
        const uint4* srcA = reinterpret_cast<const uint4*>(Wbf + (size_t)(na + 2) * (D_IN * J));
        sa0 = srcA[t];
        sa1 = srcA[t + 1024];
        const uint4* srcB = reinterpret_cast<const uint4*>(Wbf + (size_t)(na + 3) * (D_IN * J));
        sb0 = srcB[t];
        sb1 = srcB[t + 1024];
        if (ld) {
          Bna = *reinterpret_cast<const short8*>(ubf + ((size_t)b * N_IN + na + 2) * D_IN + hA * 8);
          Bnb = *reinterpret_cast<const short8*>(ubf + ((size_t)b * N_IN + na + 3) * D_IN + hA * 8);
        }
        __builtin_amdgcn_sched_barrier(0);
      }

      // 2. uhat tiles via MFMA, both n's
      f32x4 Ca[4], Cb[4];
      {
        const uint4* bufA = Wt[2 * p];
        const uint4* bufB = Wt[2 * p + 1];
        #pragma unroll
        for (int q = 0; q < 4; ++q) {
          short8 A = short8{0,0,0,0,0,0,0,0};
          if (ld) A = *reinterpret_cast<const short8*>(&bufA[aoff[q]]);
          f32x4 z = f32x4{0.f, 0.f, 0.f, 0.f};
          Ca[q] = __builtin_amdgcn_mfma_f32_16x16x32_bf16(A, Ba, z, 0, 0, 0);
        }
        #pragma unroll
        for (int q = 0; q < 4; ++q) {
          short8 A = short8{0,0,0,0,0,0,0,0};
          if (ld) A = *reinterpret_cast<const short8*>(&bufB[aoff[q]]);
          f32x4 z = f32x4{0.f, 0.f, 0.f, 0.f};
          Cb[q] = __builtin_amdgcn_mfma_f32_16x16x32_bf16(A, Bb, z, 0, 0, 0);
        }
      }

      // 3. agreement for both n's
      {
        float apa[2] = {0.f, 0.f}, apb[2] = {0.f, 0.f};
        #pragma unroll
        for (int q = 0; q < 4; ++q) {
          apa[q >> 1] += Ca[q][0]*vf[q][0] + Ca[q][1]*vf[q][1] + Ca[q][2]*vf[q][2] + Ca[q][3]*vf[q][3];
          apb[q >> 1] += Cb[q][0]*vf[q][0] + Cb[q][1]*vf[q][1] + Cb[q][2]*vf[q][2] + Cb[q][3]*vf[q][3];
        }
        #pragma unroll
        for (int p2 = 0; p2 < 2; ++p2) {
          float sa = apa[p2], sb = apb[p2];
          sa += __shfl_xor(sa, 16);
          sa += __shfl_xor(sa, 32);
          sb += __shfl_xor(sb, 16);
          sb += __shfl_xor(sb, 32);
          if (l < 16) {
            al[par][0][w * 2 + p2][l] = sa;
            al[par][1][w * 2 + p2][l] = sb;
          }
        }
      }

      // 4. write-late staging into the other quad pair
      if (more) {
        Wt[2 * (1 - p)][t] = sa0;
        Wt[2 * (1 - p)][t + 1024] = sa1;
        Wt[2 * (1 - p) + 1][t] = sb0;
        Wt[2 * (1 - p) + 1][t + 1024] = sb1;
      }

      __syncthreads();   // (B) logits staged
      {
        // softmax: all 1024 threads, t = npair*512 + b*32 + o
        int npair = t >> 9, sb2 = (t >> 5) & 15, so = t & 31;
        float x = al[par][npair][so][sb2];
        float m = x;
        #pragma unroll
        for (int k = 1; k < 32; k <<= 1) m = fmaxf(m, __shfl_xor(m, k));
        float e = __expf(x - m);
        float sm = e;
        #pragma unroll
        for (int k = 1; k < 32; k <<= 1) sm += __shfl_xor(sm, k);
        al[par][npair][so][sb2] = e / sm;
      }
      __syncthreads();   // (C) c ready
      #pragma unroll
      for (int q = 0; q < 4; ++q) {
        float ca = al[par][0][(w * 4 + q) >> 1][bl];
        float cb = al[par][1][(w * 4 + q) >> 1][bl];
        acc[q] += Ca[q] * ca + Cb[q] * cb;
      }
      // no end barrier: al parity-buffered; Wt read->overwrite separated by (B)+(C)
      Ba = Bna;
      Bb = Bnb;
    }
  } else {
    // ============ MODE 0/2: f32 load + convert, MLP-forced (round-8 proven) ============
    const bool wq = (MODE == 0) && ((t >> 8) == bq);   // this block's Wbf quarter
    const bool uq = (MODE == 0) && (w == 0) && ld;     // wave 0 writes ubf

    short8 Bcur = short8{0,0,0,0,0,0,0,0};
    {
      float wc[16];
      const float* wsrc = Wf + (size_t)n0 * (D_IN * J) + t;
      #pragma unroll
      for (int i = 0; i < 16; ++i) wc[i] = wsrc[i * J];
      float4 a4 = {0,0,0,0}, b4 = {0,0,0,0};
      if (ld) {
        const float* up = uf + ((size_t)b * N_IN + n0) * D_IN + hA * 8;
        a4 = *reinterpret_cast<const float4*>(up);
        b4 = *reinterpret_cast<const float4*>(up + 4);
      }
      __builtin_amdgcn_sched_barrier(0);   // all loads issued before packing
      uint4 d0, d1;
      pack_col(wc, d0, d1);
      Wt[0][wp(2 * t)] = d0;
      Wt[0][wp(2 * t + 1)] = d1;
      if (wq) {
        uint4* gdst = reinterpret_cast<uint4*>(Wbf + (size_t)n0 * (D_IN * J));
        gdst[wp(2 * t)] = d0;
        gdst[wp(2 * t + 1)] = d1;
      }
      if (ld) {
        Bcur[0] = (short)f2bf(a4.x); Bcur[1] = (short)f2bf(a4.y);
        Bcur[2] = (short)f2bf(a4.z); Bcur[3] = (short)f2bf(a4.w);
        Bcur[4] = (short)f2bf(b4.x); Bcur[5] = (short)f2bf(b4.y);
        Bcur[6] = (short)f2bf(b4.z); Bcur[7] = (short)f2bf(b4.w);
        if (uq)
          *reinterpret_cast<short8*>(ubf + ((size_t)b * N_IN + n0) * D_IN + hA * 8) = Bcur;
      }
    }
    __syncthreads();

    for (int nn = 0; nn < NCHUNK; ++nn) {
      const int n = n0 + nn;
      const int cur = nn & 1, nxt = cur ^ 1, par = nn & 1;
      const bool more = (nn + 1 < NCHUNK);

      // 1. issue ALL next-tile loads, then fence the scheduler
      float wc[16];
      float4 a4 = {0,0,0,0}, b4 = {0,0,0,0};
      if (more) {
        const float* wsrc = Wf + (size_t)(n + 1) * (D_IN * J) + t;
        #pragma unroll
        for (int i = 0; i < 16; ++i) wc[i] = wsrc[i * J];
        if (ld) {
          const float* up = uf + ((size_t)b * N_IN + n + 1) * D_IN + hA * 8;
          a4 = *reinterpret_cast<const float4*>(up);
          b4 = *reinterpret_cast<const float4*>(up + 4);
        }
        __builtin_amdgcn_sched_barrier(0);
      }

      // 2. uhat tiles via MFMA
      f32x4 C[4];
      const uint4* buf = Wt[cur];
      #pragma unroll
      for (int q = 0; q < 4; ++q) {
        short8 A = short8{0,0,0,0,0,0,0,0};
        if (ld) A = *reinterpret_cast<const short8*>(&buf[aoff[q]]);
        f32x4 z = f32x4{0.f, 0.f, 0.f, 0.f};
        C[q] = __builtin_amdgcn_mfma_f32_16x16x32_bf16(A, Bcur, z, 0, 0, 0);
      }

      short8 Bn = short8{0,0,0,0,0,0,0,0};
      if (more && ld) {
        Bn[0] = (short)f2bf(a4.x); Bn[1] = (short)f2bf(a4.y);
        Bn[2] = (short)f2bf(a4.z); Bn[3] = (short)f2bf(a4.w);
        Bn[4] = (short)f2bf(b4.x); Bn[5] = (short)f2bf(b4.y);
        Bn[6] = (short)f2bf(b4.z); Bn[7] = (short)f2bf(b4.w);
      }

      if (HAS_V) {
        float ap[2] = {0.f, 0.f};
        #pragma unroll
        for (int q = 0; q < 4; ++q) {
          float s = C[q][0]*vf[q][0] + C[q][1]*vf[q][1] + C[q][2]*vf[q][2] + C[q][3]*vf[q][3];
          ap[q >> 1] += s;
        }
        #pragma unroll
        for (int p = 0; p < 2; ++p) {
          float s = ap[p];
          s += __shfl_xor(s, 16);
          s += __shfl_xor(s, 32);
          if (l < 16) al[par][0][w * 2 + p][l] = s;
        }
        if (more) {
          uint4 d0, d1;
          pack_col(wc, d0, d1);
          Wt[nxt][wp(2 * t)] = d0;
          Wt[nxt][wp(2 * t + 1)] = d1;
          if (wq) {
            uint4* gdst = reinterpret_cast<uint4*>(Wbf + (size_t)(n + 1) * (D_IN * J));
            gdst[wp(2 * t)] = d0;
            gdst[wp(2 * t + 1)] = d1;
          }
          if (ld && uq)
            *reinterpret_cast<short8*>(ubf + ((size_t)b * N_IN + n + 1) * D_IN + hA * 8) = Bn;
        }
        __syncthreads();   // (B)
        if (t < 512) {
          int sb = t >> 5, so = t & 31;
          float x = al[par][0][so][sb];
          float m = x;
          #pragma unroll
          for (int k = 1; k < 32; k <<= 1) m = fmaxf(m, __shfl_xor(m, k));
          float e = __expf(x - m);
          float sm = e;
          #pragma unroll
          for (int k = 1; k < 32; k <<= 1) sm += __shfl_xor(sm, k);
          al[par][0][so][sb] = e / sm;
        }
        __syncthreads();   // (C)
        #pragma unroll
        for (int q = 0; q < 4; ++q) {
          float c = al[par][0][(w * 4 + q) >> 1][bl];
          acc[q] += C[q] * c;
        }
      } else {
        #pragma unroll
        for (int q = 0; q < 4; ++q) acc[q] += C[q];
        if (more) {
          uint4 d0, d1;
          pack_col(wc, d0, d1);
          Wt[nxt][wp(2 * t)] = d0;
          Wt[nxt][wp(2 * t + 1)] = d1;
          if (wq) {
            uint4* gdst = reinterpret_cast<uint4*>(Wbf + (size_t)(n + 1) * (D_IN * J));
            gdst[wp(2 * t)] = d0;
            gdst[wp(2 * t + 1)] = d1;
          }
          if (ld && uq)
            *reinterpret_cast<short8*>(ubf + ((size_t)b * N_IN + n + 1) * D_IN + hA * 8) = Bn;
        }
        __syncthreads();
      }
      Bcur = Bn;
    }
  }

  // epilogue: part[cx][j][b] (transposed -> coalesced b-fast writes)
  #pragma unroll
  for (int q = 0; q < 4; ++q) {
    int jbase = (w * 4 + q) * 16 + h * 4;
    #pragma unroll
    for (int r = 0; r < 4; ++r)
      part[((size_t)cx * J + jbase + r) * 64 + b] = acc[q][r];
  }
}

// Fused chunk-reduce + squash. grid = 128 (o x b-quadrant), 1024 threads.
template<int NC>
__global__ __launch_bounds__(1024)
void rsq_kernel(const float* __restrict__ part, const float* __restrict__ addv,
                float* __restrict__ out, float prescale)
{
  __shared__ float ps[2][32][17];
  __shared__ float vl[32][17];
  __shared__ float scl[16];
  const int o  = blockIdx.x >> 2;
  const int bq = blockIdx.x & 3;
  const int t  = threadIdx.x;
  {
    const int bb = t & 15;
    const int kk = (t >> 4) & 31;
    const int ch = t >> 9;         // 0/1
    const float* p = part + (size_t)(o * 32 + kk) * 64 + bq * 16 + bb;
    float s = 0.f;
    #pragma unroll 8
    for (int c = ch * (NC / 2); c < (ch + 1) * (NC / 2); ++c)
      s += p[(size_t)c * (J * 64)];
    ps[ch][kk][bb] = s;
  }
  __syncthreads();
  if (t < 512) {
    int kk = t >> 4, bb = t & 15;
    vl[kk][bb] = (ps[0][kk][bb] + ps[1][kk][bb]) * prescale;
  }
  __syncthreads();
  if (t < 16) {
    float n2 = 0.f;
    #pragma unroll
    for (int k = 0; k < 32; ++k) { float x = vl[k][t]; n2 += x * x; }
    scl[t] = sqrtf(n2) / (1.f + n2);
  }
  __syncthreads();
  if (t < 512) {
    int bb = t >> 5, kk = t & 31;
    int idx = (bq * 16 + bb) * J + o * 32 + kk;
    float val = scl[bb] * vl[kk][bb];
    if (addv) val += addv[idx];
    out[idx] = val;
  }
}

extern "C" void kernel_launch(void* const* d_in, const int* in_sizes, int n_in,
                              void* d_out, int out_size, void* d_ws, size_t ws_size,
                              hipStream_t stream)
{
  const float* u = (const float*)d_in[0];
  const float* W = (const float*)d_in[1];
  float* out = (float*)d_out;
  char* ws = (char*)d_ws;

  const size_t WBF_B = (size_t)N_IN * D_IN * J * 2;        // 64 MB
  const size_t UBF_B = (size_t)BATCH * N_IN * D_IN * 2;    // 4 MB
  const size_t SMALL = 2ull * BATCH * J * 4;               // v0+vs
  const size_t PART64 = (size_t)64 * J * 64 * 4;           // 16.7 MB (NC=64)

  if (ws_size >= WBF_B + UBF_B + PART64 + SMALL) {
    short* Wbf = (short*)ws;
    short* ubf = (short*)(ws + WBF_B);
    float* part = (float*)(ws + WBF_B + UBF_B);
    float* v0 = part + (size_t)64 * J * 64;
    float* vs = v0 + BATCH * J;
    // r=0: pass0 converts + emits Wbf/ubf (MLP-forced loads)
    pass_kernel<false, 0, 32><<<256, 1024, 0, stream>>>(u, W, Wbf, ubf, nullptr, part);
    rsq_kernel<64><<<128, 1024, 0, stream>>>(part, nullptr, v0, 1.f / 32.f);
    // r=1,2: paired-n MODE1
    pass_kernel<true, 1, 32><<<256, 1024, 0, stream>>>(u, W, Wbf, ubf, v0, part);
    rsq_kernel<64><<<128, 1024, 0, stream>>>(part, v0, vs, 1.f);
    pass_kernel<true, 1, 32><<<256, 1024, 0, stream>>>(u, W, Wbf, ubf, vs, part);
    rsq_kernel<64><<<128, 1024, 0, stream>>>(part, nullptr, out, 1.f);
  } else if (ws_size >= PART64 + SMALL) {
    float* part = (float*)ws;
    float* v0 = part + (size_t)64 * J * 64;
    float* vs = v0 + BATCH * J;
    pass_kernel<false, 2, 32><<<256, 1024, 0, stream>>>(u, W, nullptr, nullptr, nullptr, part);
    rsq_kernel<64><<<128, 1024, 0, stream>>>(part, nullptr, v0, 1.f / 32.f);
    pass_kernel<true, 2, 32><<<256, 1024, 0, stream>>>(u, W, nullptr, nullptr, v0, part);
    rsq_kernel<64><<<128, 1024, 0, stream>>>(part, v0, vs, 1.f);
    pass_kernel<true, 2, 32><<<256, 1024, 0, stream>>>(u, W, nullptr, nullptr, vs, part);
    rsq_kernel<64><<<128, 1024, 0, stream>>>(part, nullptr, out, 1.f);
  } else {
    float* part = (float*)ws;
    float* v0 = part + (size_t)16 * J * 64;
    float* vs = v0 + BATCH * J;
    pass_kernel<false, 2, 128><<<64, 1024, 0, stream>>>(u, W, nullptr, nullptr, nullptr, part);
    rsq_kernel<16><<<128, 1024, 0, stream>>>(part, nullptr, v0, 1.f / 32.f);
    pass_kernel<true, 2, 128><<<64, 1024, 0, stream>>>(u, W, nullptr, nullptr, v0, part);
    rsq_kernel<16><<<128, 1024, 0, stream>>>(part, v0, vs, 1.f);
    pass_kernel<true, 2, 128><<<64, 1024, 0, stream>>>(u, W, nullptr, nullptr, vs, part);
    rsq_kernel<16><<<128, 1024, 0, stream>>>(part, nullptr, out, 1.f);
  }
}